// Round 1
// baseline (233.835 us; speedup 1.0000x reference)
//
#include <hip/hip_runtime.h>
#include <math.h>
#include <float.h>

#define BS 256
#define MAXC 31
#define MAXGT (BS * MAXC)   // 7936 max gt rows per block
typedef unsigned long long u64;
typedef unsigned short u16;
typedef unsigned int u32;

// ws layout (nb = 1024):
//   [0,4)            u32 arrived      (memset 0)
//   [4,8)            u32 done         (memset 0)
//   [64, 64+8K)      u64 state[nb]    (memset 0)  -> (ready<<32)|exclusiveOffset
//   [12288, 16384)   u32 blockSums[nb]            (no init: each block writes own)
//   [16384, 32768)   float partials[nb*4]         (no init: each block writes own)
//
// Single fused kernel. Cross-block scan done in-kernel by the LAST-arriving
// block (atomic ticket); all 1024 blocks are guaranteed co-resident
// (__launch_bounds__(256,4) -> >=4 blocks/CU * 256 CU = 1024, LDS ~20KB -> 7/CU),
// so spinning on the per-block state word cannot deadlock.

__global__ void __launch_bounds__(BS, 4)
fused_all(const float* __restrict__ pred, const float* __restrict__ gt,
          const int* __restrict__ counts,
          u32* arrived, u32* done, u64* state, u32* blockSums,
          float* partials, float* out, int N) {
    const int t = threadIdx.x;
    const int b = blockIdx.x;
    const int nb = gridDim.x;
    const int i = b * BS + t;
    const int lane = t & 63, w = t >> 6;

    __shared__ u16 ownerMap[MAXGT];     // 15872 B
    __shared__ float2 pxy[BS];          // 2048 B
    __shared__ u64 bestLds[BS];         // 2048 B
    __shared__ int waveTot[BS / 64];
    __shared__ int sTotal;
    __shared__ int sBase;
    __shared__ int sFlag;
    __shared__ float red[BS / 64][4];
    __shared__ double dred[BS / 64][4];

    // ---- intra-block exclusive scan of counts ----
    const int c = (i < N) ? counts[i] : 0;
    int incl = c;
    for (int o = 1; o < 64; o <<= 1) {
        int x = __shfl_up(incl, o, 64);
        if (lane >= o) incl += x;
    }
    if (lane == 63) waveTot[w] = incl;
    __syncthreads();
    int wbase = 0;
    for (int ww = 0; ww < w; ++ww) wbase += waveTot[ww];
    const int localStart = wbase + incl - c;

    // thread BS-1 knows the block total in-register: publish immediately.
    if (t == BS - 1) {
        const int tot = localStart + c;
        sTotal = tot;
        atomicExch(&blockSums[b], (u32)tot);
        __threadfence();
        const u32 old = atomicAdd(arrived, 1u);
        sFlag = (old == (u32)(nb - 1)) ? 1 : 0;
    }

    // overlap: per-block setup while other blocks publish their sums
    bestLds[t] = ~0ULL;
    if (i < N) pxy[t] = reinterpret_cast<const float2*>(pred)[(size_t)i * 3];
    for (int j = 0; j < c; ++j) ownerMap[localStart + j] = (u16)t;
    __syncthreads();

    // ---- cross-block exclusive scan ----
    if (sFlag) {
        // last-arriving block: all sums are published (release fences above).
        __threadfence();
        if (t < 64) {
            const int bi = t * 16;
            u32 v[16];
            int s = 0;
#pragma unroll
            for (int k = 0; k < 16; ++k) {
                v[k] = atomicAdd(&blockSums[bi + k], 0u);   // coherent load
                s += (int)v[k];
            }
            int isc = s;
            for (int o = 1; o < 64; o <<= 1) {
                int x = __shfl_up(isc, o, 64);
                if (t >= o) isc += x;
            }
            int excl = isc - s;
#pragma unroll
            for (int k = 0; k < 16; ++k) {
                if (bi + k == b) sBase = excl;               // own base, no self-spin
                atomicExch(&state[bi + k], (1ULL << 32) | (u64)(u32)excl);
                excl += (int)v[k];
            }
        }
    } else {
        if (t == 0) {
            u64 st;
            while (((st = atomicAdd(&state[b], 0ULL)) >> 32) == 0ULL)
                __builtin_amdgcn_s_sleep(2);
            sBase = (int)(u32)st;
        }
    }
    __syncthreads();

    const int base = sBase;
    const int blockTotal = sTotal;
    const float2* gxy = reinterpret_cast<const float2*>(gt);

    // ---- tile loop, unrolled x4: independent loads + LDS atomicMin ----
    for (int tile = 0; tile < blockTotal; tile += BS * 4) {
        int j[4]; float2 g[4]; bool valid[4];
#pragma unroll
        for (int u = 0; u < 4; ++u) {
            j[u] = tile + u * BS + t;
            valid[u] = j[u] < blockTotal;
            if (valid[u]) g[u] = gxy[(size_t)(base + j[u]) * 3];
        }
#pragma unroll
        for (int u = 0; u < 4; ++u) {
            if (valid[u]) {
                const int owner = (int)ownerMap[j[u]];
                const float2 p = pxy[owner];
                const float dx = p.x - g[u].x, dy = p.y - g[u].y;
                const float d2 = dx * dx + dy * dy;  // >=0: IEEE-monotone bits
                const u64 key = ((u64)__float_as_uint(d2) << 32)
                              | (u32)(base + j[u]);
                atomicMin(&bestLds[owner], key);     // min d2, then lowest row
            }
        }
    }
    __syncthreads();

    // ---- per-pred epilogue ----
    float lp = 0.f, la = 0.f, lw = 0.f, ls = 0.f;
    if (i < N && c > 0) {
        const u64 key = bestLds[t];
        const float d2 = __uint_as_float((u32)(key >> 32));
        const int bj = (int)(key & 0xffffffffu);
        lp = 1.0f - expf(-d2 / 0.045f);  // max resp == exp(-min d2/(2 sigma^2))

        const float* p = pred + (size_t)i * 6;
        const float2 p23 = *reinterpret_cast<const float2*>(p + 2);
        const float2 p45 = *reinterpret_cast<const float2*>(p + 4);
        const float* ng = gt + (size_t)bj * 6;
        const float2 g23 = *reinterpret_cast<const float2*>(ng + 2);
        const float2 g45 = *reinterpret_cast<const float2*>(ng + 4);

        la = fabsf(p23.x - g23.x) + fabsf(p23.y - g23.y);
        const float d = p45.x - g45.x;
        const float ad = fabsf(d);
        lw = (ad < 1.0f) ? 0.5f * d * d : ad - 0.5f;
        const float x = p45.y;
        if (g45.y > 0.0f) {
            ls = fmaxf(x, 0.0f) - x * g45.y + log1pf(expf(-fabsf(x)));
        }
    }

    for (int o = 32; o > 0; o >>= 1) {
        lp += __shfl_down(lp, o, 64);
        la += __shfl_down(la, o, 64);
        lw += __shfl_down(lw, o, 64);
        ls += __shfl_down(ls, o, 64);
    }
    if (lane == 0) { red[w][0] = lp; red[w][1] = la; red[w][2] = lw; red[w][3] = ls; }
    __syncthreads();
    if (t == 0) {
        float s0 = 0, s1 = 0, s2 = 0, s3 = 0;
        for (int ww = 0; ww < BS / 64; ++ww) {
            s0 += red[ww][0]; s1 += red[ww][1]; s2 += red[ww][2]; s3 += red[ww][3];
        }
        atomicExch(&partials[b * 4 + 0], s0);
        atomicExch(&partials[b * 4 + 1], s1);
        atomicExch(&partials[b * 4 + 2], s2);
        atomicExch(&partials[b * 4 + 3], s3);
        __threadfence();
        const u32 old = atomicAdd(done, 1u);
        sFlag = (old == (u32)(nb - 1)) ? 1 : 0;   // safe reuse: all prior reads done
    }
    __syncthreads();

    // ---- final reduce by the last-finishing block (deterministic f64 order) ----
    if (sFlag) {
        __threadfence();
        double a0 = 0, a1 = 0, a2 = 0, a3 = 0;
        for (int r = t; r < nb; r += BS) {       // rows t, t+256, t+512, t+768
            a0 += (double)atomicAdd(&partials[r * 4 + 0], 0.0f);
            a1 += (double)atomicAdd(&partials[r * 4 + 1], 0.0f);
            a2 += (double)atomicAdd(&partials[r * 4 + 2], 0.0f);
            a3 += (double)atomicAdd(&partials[r * 4 + 3], 0.0f);
        }
        for (int o = 32; o > 0; o >>= 1) {
            a0 += __shfl_down(a0, o, 64);
            a1 += __shfl_down(a1, o, 64);
            a2 += __shfl_down(a2, o, 64);
            a3 += __shfl_down(a3, o, 64);
        }
        if (lane == 0) { dred[w][0] = a0; dred[w][1] = a1; dred[w][2] = a2; dred[w][3] = a3; }
        __syncthreads();
        if (t == 0) {
            double t0 = 0, t1 = 0, t2 = 0, t3 = 0;
            for (int ww = 0; ww < BS / 64; ++ww) {
                t0 += dred[ww][0]; t1 += dred[ww][1]; t2 += dred[ww][2]; t3 += dred[ww][3];
            }
            const double inv = 1.0 / (double)N;
            const float flp = (float)(t0 * inv);
            const float fla = (float)(t1 * inv);
            const float flw = (float)(t2 * inv);
            const float fls = (float)(t3 * inv);
            out[0] = flp; out[1] = fla; out[2] = flw; out[3] = fls;
            out[4] = flp + fla + flw + 0.5f * fls;
        }
    }
}

extern "C" void kernel_launch(void* const* d_in, const int* in_sizes, int n_in,
                              void* d_out, int out_size, void* d_ws, size_t ws_size,
                              hipStream_t stream) {
    const float* pred = (const float*)d_in[0];
    const float* gt = (const float*)d_in[1];
    const int* counts = (const int*)d_in[2];
    float* out = (float*)d_out;

    const int N = in_sizes[2];
    const int numBlocks = (N + BS - 1) / BS;  // 1024

    char* ws = (char*)d_ws;
    u32* arrived = (u32*)ws;
    u32* done = (u32*)(ws + 4);
    u64* state = (u64*)(ws + 64);
    u32* blockSums = (u32*)(ws + 12288);
    float* partials = (float*)(ws + 16384);

    // zero only the sync words + per-block state (8.3 KB): graph-capturable
    hipMemsetAsync(d_ws, 0, 64 + (size_t)numBlocks * sizeof(u64), stream);
    fused_all<<<numBlocks, BS, 0, stream>>>(pred, gt, counts, arrived, done,
                                            state, blockSums, partials, out, N);
}

// Round 2
// 168.573 us; speedup vs baseline: 1.3871x; 1.3871x over previous
//
#include <hip/hip_runtime.h>
#include <math.h>
#include <float.h>

#define BS 256
#define CHUNK 2048          // gt rows staged per LDS tile (16 KB)
typedef unsigned long long u64;

// ws layout (nb = 1024):
//   [0, 4K)        int blockSums[nb]
//   [4K, 8K)       int blockOffsets[nb]
//   [8K, 24K)      float4 partials[nb]   (lp, la, lw, ls per block)

__global__ void block_sum_kernel(const int* __restrict__ counts,
                                 int* __restrict__ blockSums, int N) {
    int i = blockIdx.x * BS + threadIdx.x;
    int v = (i < N) ? counts[i] : 0;
    for (int o = 32; o > 0; o >>= 1) v += __shfl_down(v, o, 64);
    __shared__ int ws[BS / 64];
    int lane = threadIdx.x & 63, w = threadIdx.x >> 6;
    if (lane == 0) ws[w] = v;
    __syncthreads();
    if (threadIdx.x == 0) {
        int s = 0;
        for (int ww = 0; ww < BS / 64; ++ww) s += ws[ww];
        blockSums[blockIdx.x] = s;
    }
}

__global__ void scan_kernel(const int* __restrict__ blockSums,
                            int* __restrict__ blockOffsets, int nb) {
    __shared__ int tmp[1024];
    int t = threadIdx.x;
    int v = (t < nb) ? blockSums[t] : 0;
    tmp[t] = v;
    __syncthreads();
    for (int off = 1; off < 1024; off <<= 1) {
        int x = (t >= off) ? tmp[t - off] : 0;
        __syncthreads();
        tmp[t] += x;
        __syncthreads();
    }
    if (t < nb) blockOffsets[t] = tmp[t] - v;  // exclusive
}

// Block b owns pred rows [b*256, b*256+256) and their contiguous gt range.
// v2: no ownerMap, no LDS atomics. Stage gt xy in LDS chunks (coalesced),
// then each thread min-scans ONLY its own segment's rows in ascending order
// (strict < keeps the lowest global row on d2 ties, matching the reference).
__global__ void __launch_bounds__(BS)
fused_kernel(const float* __restrict__ pred, const float* __restrict__ gt,
             const int* __restrict__ counts, const int* __restrict__ blockOffsets,
             float4* __restrict__ partials, int N) {
    const int t = threadIdx.x;
    const int b = blockIdx.x;
    const int i = b * BS + t;
    const int lane = t & 63, w = t >> 6;

    __shared__ float2 chunkXY[CHUNK];   // 16384 B
    __shared__ int waveTot[BS / 64];
    __shared__ int sTotal;
    __shared__ float red[BS / 64][4];

    // ---- intra-block exclusive scan of counts ----
    const int c = (i < N) ? counts[i] : 0;
    int incl = c;
    for (int o = 1; o < 64; o <<= 1) {
        int x = __shfl_up(incl, o, 64);
        if (lane >= o) incl += x;
    }
    if (lane == 63) waveTot[w] = incl;
    __syncthreads();
    int wbase = 0;
    for (int ww = 0; ww < w; ++ww) wbase += waveTot[ww];
    const int myStart = wbase + incl - c;       // local gt row of my segment
    const int myEnd = myStart + c;
    if (t == BS - 1) sTotal = myEnd;
    __syncthreads();

    const int base = blockOffsets[b];
    const int blockTotal = sTotal;
    const float2* gxy = reinterpret_cast<const float2*>(gt);

    const float2 myp = (i < N)
        ? reinterpret_cast<const float2*>(pred)[(size_t)i * 3]
        : make_float2(0.f, 0.f);

    float best = FLT_MAX;
    int bestRow = 0;                            // global gt row of nearest

    for (int chunkLo = 0; chunkLo < blockTotal; chunkLo += CHUNK) {
        // coalesced stage: 8 independent predicated loads per thread
#pragma unroll
        for (int u = 0; u < CHUNK / BS; ++u) {
            const int j = u * BS + t;
            const int gj = chunkLo + j;
            if (gj < blockTotal) chunkXY[j] = gxy[(size_t)(base + gj) * 3];
        }
        __syncthreads();
        // my segment ∩ this chunk (a 31-row segment spans ≤ 2 chunks)
        const int lo = myStart > chunkLo ? myStart : chunkLo;
        const int hiLim = chunkLo + CHUNK;
        const int hi = myEnd < hiLim ? myEnd : hiLim;
        for (int j = lo; j < hi; ++j) {
            const float2 g = chunkXY[j - chunkLo];
            const float dx = myp.x - g.x, dy = myp.y - g.y;
            const float d2 = dx * dx + dy * dy;
            if (d2 < best) { best = d2; bestRow = base + j; }
        }
        __syncthreads();
    }

    // ---- per-pred epilogue ----
    float lp = 0.f, la = 0.f, lw = 0.f, ls = 0.f;
    if (i < N && c > 0) {
        lp = 1.0f - expf(-best / 0.045f);  // max resp == exp(-min d2/(2 sigma^2))

        const float* p = pred + (size_t)i * 6;
        const float2 p23 = *reinterpret_cast<const float2*>(p + 2);
        const float2 p45 = *reinterpret_cast<const float2*>(p + 4);
        const float* ng = gt + (size_t)bestRow * 6;
        const float2 g23 = *reinterpret_cast<const float2*>(ng + 2);
        const float2 g45 = *reinterpret_cast<const float2*>(ng + 4);

        la = fabsf(p23.x - g23.x) + fabsf(p23.y - g23.y);
        const float d = p45.x - g45.x;
        const float ad = fabsf(d);
        lw = (ad < 1.0f) ? 0.5f * d * d : ad - 0.5f;
        const float x = p45.y;
        if (g45.y > 0.0f) {
            ls = fmaxf(x, 0.0f) - x * g45.y + log1pf(expf(-fabsf(x)));
        }
    }

    for (int o = 32; o > 0; o >>= 1) {
        lp += __shfl_down(lp, o, 64);
        la += __shfl_down(la, o, 64);
        lw += __shfl_down(lw, o, 64);
        ls += __shfl_down(ls, o, 64);
    }
    if (lane == 0) { red[w][0] = lp; red[w][1] = la; red[w][2] = lw; red[w][3] = ls; }
    __syncthreads();
    if (t == 0) {
        float s0 = 0, s1 = 0, s2 = 0, s3 = 0;
        for (int ww = 0; ww < BS / 64; ++ww) {
            s0 += red[ww][0]; s1 += red[ww][1]; s2 += red[ww][2]; s3 += red[ww][3];
        }
        partials[b] = make_float4(s0, s1, s2, s3);  // distinct slot: no atomics
    }
}

// Reduce 1024 per-block partials in one block; f64 accumulation.
__global__ void finalize_kernel(const float4* __restrict__ partials,
                                float* __restrict__ out, int nb, int N) {
    const int t = threadIdx.x;
    const int lane = t & 63, w = t >> 6;
    double s0 = 0, s1 = 0, s2 = 0, s3 = 0;
    if (t < nb) {
        const float4 v = partials[t];
        s0 = v.x; s1 = v.y; s2 = v.z; s3 = v.w;
    }
    for (int o = 32; o > 0; o >>= 1) {
        s0 += __shfl_down(s0, o, 64);
        s1 += __shfl_down(s1, o, 64);
        s2 += __shfl_down(s2, o, 64);
        s3 += __shfl_down(s3, o, 64);
    }
    __shared__ double red[16][4];
    if (lane == 0) { red[w][0] = s0; red[w][1] = s1; red[w][2] = s2; red[w][3] = s3; }
    __syncthreads();
    if (t == 0) {
        double t0 = 0, t1 = 0, t2 = 0, t3 = 0;
        for (int ww = 0; ww < blockDim.x / 64; ++ww) {
            t0 += red[ww][0]; t1 += red[ww][1]; t2 += red[ww][2]; t3 += red[ww][3];
        }
        const double inv = 1.0 / (double)N;
        const float lp = (float)(t0 * inv);
        const float la = (float)(t1 * inv);
        const float lw = (float)(t2 * inv);
        const float ls = (float)(t3 * inv);
        out[0] = lp; out[1] = la; out[2] = lw; out[3] = ls;
        out[4] = lp + la + lw + 0.5f * ls;
    }
}

extern "C" void kernel_launch(void* const* d_in, const int* in_sizes, int n_in,
                              void* d_out, int out_size, void* d_ws, size_t ws_size,
                              hipStream_t stream) {
    const float* pred = (const float*)d_in[0];
    const float* gt = (const float*)d_in[1];
    const int* counts = (const int*)d_in[2];
    float* out = (float*)d_out;

    const int N = in_sizes[2];
    const int numBlocks = (N + BS - 1) / BS;  // 1024

    int* blockSums = (int*)d_ws;
    int* blockOffsets = (int*)((char*)d_ws + 4096);
    float4* partials = (float4*)((char*)d_ws + 8192);

    block_sum_kernel<<<numBlocks, BS, 0, stream>>>(counts, blockSums, N);
    scan_kernel<<<1, 1024, 0, stream>>>(blockSums, blockOffsets, numBlocks);
    fused_kernel<<<numBlocks, BS, 0, stream>>>(pred, gt, counts, blockOffsets,
                                               partials, N);
    finalize_kernel<<<1, 1024, 0, stream>>>(partials, out, numBlocks, N);
}

// Round 3
// 165.259 us; speedup vs baseline: 1.4150x; 1.0201x over previous
//
#include <hip/hip_runtime.h>
#include <math.h>
#include <float.h>

#define BS 256
#define CHUNK 4096          // gt rows staged per LDS tile (32 KB) -> 4 blocks/CU
typedef unsigned long long u64;

// ws layout (nb = 1024):
//   [0, 4K)        int blockSums[nb]
//   [8K, 24K)      float4 partials[nb]   (lp, la, lw, ls per block)

__global__ void block_sum_kernel(const int* __restrict__ counts,
                                 int* __restrict__ blockSums, int N) {
    int i = blockIdx.x * BS + threadIdx.x;
    int v = (i < N) ? counts[i] : 0;
    for (int o = 32; o > 0; o >>= 1) v += __shfl_down(v, o, 64);
    __shared__ int ws[BS / 64];
    int lane = threadIdx.x & 63, w = threadIdx.x >> 6;
    if (lane == 0) ws[w] = v;
    __syncthreads();
    if (threadIdx.x == 0) {
        int s = 0;
        for (int ww = 0; ww < BS / 64; ++ww) s += ws[ww];
        blockSums[blockIdx.x] = s;
    }
}

// Block b owns pred rows [b*256, b*256+256) and their contiguous gt range.
// v3: no scan kernel. Each block computes its own exclusive base by summing
// blockSums[0..b) (L2-hot, 4 coalesced loads/thread) inside the existing
// prologue barrier. Inner loop: stage gt xy in LDS chunks (coalesced), each
// thread min-scans ONLY its own segment's rows in ascending order
// (strict < keeps the lowest global row on d2 ties, matching the reference).
__global__ void __launch_bounds__(BS)
fused_kernel(const float* __restrict__ pred, const float* __restrict__ gt,
             const int* __restrict__ counts, const int* __restrict__ blockSums,
             float4* __restrict__ partials, int N) {
    const int t = threadIdx.x;
    const int b = blockIdx.x;
    const int i = b * BS + t;
    const int lane = t & 63, w = t >> 6;

    __shared__ float2 chunkXY[CHUNK];   // 32768 B
    __shared__ int waveTot[BS / 64];
    __shared__ int basePart[BS / 64];
    __shared__ int sTotal;
    __shared__ float red[BS / 64][4];

    // ---- intra-block exclusive scan of counts ----
    const int c = (i < N) ? counts[i] : 0;
    int incl = c;
    for (int o = 1; o < 64; o <<= 1) {
        int x = __shfl_up(incl, o, 64);
        if (lane >= o) incl += x;
    }
    if (lane == 63) waveTot[w] = incl;

    // ---- self-scan of blockSums[0..b): my global gt base ----
    int acc = 0;
#pragma unroll
    for (int k = 0; k < 4; ++k) {
        const int idx = t + BS * k;
        if (idx < b) acc += blockSums[idx];
    }
    for (int o = 32; o > 0; o >>= 1) acc += __shfl_down(acc, o, 64);
    if (lane == 0) basePart[w] = acc;
    __syncthreads();

    int wbase = 0;
    for (int ww = 0; ww < w; ++ww) wbase += waveTot[ww];
    const int myStart = wbase + incl - c;       // local gt row of my segment
    const int myEnd = myStart + c;
    const int base = basePart[0] + basePart[1] + basePart[2] + basePart[3];
    if (t == BS - 1) sTotal = myEnd;
    __syncthreads();

    const int blockTotal = sTotal;
    const float2* gxy = reinterpret_cast<const float2*>(gt);

    const float2 myp = (i < N)
        ? reinterpret_cast<const float2*>(pred)[(size_t)i * 3]
        : make_float2(0.f, 0.f);

    float best = FLT_MAX;
    int bestRow = 0;                            // global gt row of nearest

    for (int chunkLo = 0; chunkLo < blockTotal; chunkLo += CHUNK) {
        // coalesced stage: 16 independent predicated loads per thread
#pragma unroll
        for (int u = 0; u < CHUNK / BS; ++u) {
            const int j = u * BS + t;
            const int gj = chunkLo + j;
            if (gj < blockTotal) chunkXY[j] = gxy[(size_t)(base + gj) * 3];
        }
        __syncthreads();
        // my segment ∩ this chunk (a 31-row segment spans <= 2 chunks)
        const int lo = myStart > chunkLo ? myStart : chunkLo;
        const int hiLim = chunkLo + CHUNK;
        const int hi = myEnd < hiLim ? myEnd : hiLim;
        for (int j = lo; j < hi; ++j) {
            const float2 g = chunkXY[j - chunkLo];
            const float dx = myp.x - g.x, dy = myp.y - g.y;
            const float d2 = dx * dx + dy * dy;
            if (d2 < best) { best = d2; bestRow = base + j; }
        }
        __syncthreads();
    }

    // ---- per-pred epilogue ----
    float lp = 0.f, la = 0.f, lw = 0.f, ls = 0.f;
    if (i < N && c > 0) {
        lp = 1.0f - expf(-best / 0.045f);  // max resp == exp(-min d2/(2 sigma^2))

        const float* p = pred + (size_t)i * 6;
        const float2 p23 = *reinterpret_cast<const float2*>(p + 2);
        const float2 p45 = *reinterpret_cast<const float2*>(p + 4);
        const float* ng = gt + (size_t)bestRow * 6;
        const float2 g23 = *reinterpret_cast<const float2*>(ng + 2);
        const float2 g45 = *reinterpret_cast<const float2*>(ng + 4);

        la = fabsf(p23.x - g23.x) + fabsf(p23.y - g23.y);
        const float d = p45.x - g45.x;
        const float ad = fabsf(d);
        lw = (ad < 1.0f) ? 0.5f * d * d : ad - 0.5f;
        const float x = p45.y;
        if (g45.y > 0.0f) {
            ls = fmaxf(x, 0.0f) - x * g45.y + log1pf(expf(-fabsf(x)));
        }
    }

    for (int o = 32; o > 0; o >>= 1) {
        lp += __shfl_down(lp, o, 64);
        la += __shfl_down(la, o, 64);
        lw += __shfl_down(lw, o, 64);
        ls += __shfl_down(ls, o, 64);
    }
    if (lane == 0) { red[w][0] = lp; red[w][1] = la; red[w][2] = lw; red[w][3] = ls; }
    __syncthreads();
    if (t == 0) {
        float s0 = 0, s1 = 0, s2 = 0, s3 = 0;
        for (int ww = 0; ww < BS / 64; ++ww) {
            s0 += red[ww][0]; s1 += red[ww][1]; s2 += red[ww][2]; s3 += red[ww][3];
        }
        partials[b] = make_float4(s0, s1, s2, s3);  // distinct slot: no atomics
    }
}

// Reduce 1024 per-block partials in one block; f64 accumulation.
__global__ void finalize_kernel(const float4* __restrict__ partials,
                                float* __restrict__ out, int nb, int N) {
    const int t = threadIdx.x;
    const int lane = t & 63, w = t >> 6;
    double s0 = 0, s1 = 0, s2 = 0, s3 = 0;
    if (t < nb) {
        const float4 v = partials[t];
        s0 = v.x; s1 = v.y; s2 = v.z; s3 = v.w;
    }
    for (int o = 32; o > 0; o >>= 1) {
        s0 += __shfl_down(s0, o, 64);
        s1 += __shfl_down(s1, o, 64);
        s2 += __shfl_down(s2, o, 64);
        s3 += __shfl_down(s3, o, 64);
    }
    __shared__ double red[16][4];
    if (lane == 0) { red[w][0] = s0; red[w][1] = s1; red[w][2] = s2; red[w][3] = s3; }
    __syncthreads();
    if (t == 0) {
        double t0 = 0, t1 = 0, t2 = 0, t3 = 0;
        for (int ww = 0; ww < blockDim.x / 64; ++ww) {
            t0 += red[ww][0]; t1 += red[ww][1]; t2 += red[ww][2]; t3 += red[ww][3];
        }
        const double inv = 1.0 / (double)N;
        const float lp = (float)(t0 * inv);
        const float la = (float)(t1 * inv);
        const float lw = (float)(t2 * inv);
        const float ls = (float)(t3 * inv);
        out[0] = lp; out[1] = la; out[2] = lw; out[3] = ls;
        out[4] = lp + la + lw + 0.5f * ls;
    }
}

extern "C" void kernel_launch(void* const* d_in, const int* in_sizes, int n_in,
                              void* d_out, int out_size, void* d_ws, size_t ws_size,
                              hipStream_t stream) {
    const float* pred = (const float*)d_in[0];
    const float* gt = (const float*)d_in[1];
    const int* counts = (const int*)d_in[2];
    float* out = (float*)d_out;

    const int N = in_sizes[2];
    const int numBlocks = (N + BS - 1) / BS;  // 1024

    int* blockSums = (int*)d_ws;
    float4* partials = (float4*)((char*)d_ws + 8192);

    block_sum_kernel<<<numBlocks, BS, 0, stream>>>(counts, blockSums, N);
    fused_kernel<<<numBlocks, BS, 0, stream>>>(pred, gt, counts, blockSums,
                                               partials, N);
    finalize_kernel<<<1, 1024, 0, stream>>>(partials, out, numBlocks, N);
}